// Round 6
// baseline (681.410 us; speedup 1.0000x reference)
//
#include <hip/hip_runtime.h>
#include <hip/hip_fp16.h>

#define N_NODES 50000
#define N_EDGES 800000
#define EL (N_EDGES + N_NODES) /* 850000 */
#define F_IN 767
#define HID 256
#define NHEAD 8
#define KSTEPS 24 /* ceil(767/32) */
#define NB_SCAN 49 /* ceil(50000/1024) */

typedef __attribute__((ext_vector_type(8))) short short8;
typedef __attribute__((ext_vector_type(4))) float f32x4;

static __device__ __forceinline__ unsigned short f2bf(float f) {
  unsigned int u = __float_as_uint(f);
  unsigned int r = (u + 0x7fffu + ((u >> 16) & 1u)) >> 16;
  return (unsigned short)r;
}
static __device__ __forceinline__ float bf2f(unsigned short h) {
  return __uint_as_float(((unsigned int)h) << 16);
}

// ---- prep: split W into bf16 hi/lo and repack into MFMA fragment order ----
__global__ __launch_bounds__(256) void prep_kernel(
    const float* __restrict__ W, short* __restrict__ Wh, short* __restrict__ Wl) {
  int idx = blockIdx.x * 256 + threadIdx.x;  // 768*256 threads
  int k = idx >> 8, n = idx & 255;
  float v = (k < F_IN) ? W[k * HID + n] : 0.f;
  unsigned short h = f2bf(v);
  float lf = v - bf2f(h);
  unsigned short lo = f2bf(lf);
  int ks = k >> 5, oct = (k >> 3) & 3, j = k & 7;
  int nf = n >> 4;
  int l = (n & 15) | (oct << 4);
  int addr = ((ks * 16 + nf) * 64 + l) * 8 + j;
  Wh[addr] = (short)h;
  Wl[addr] = (short)lo;
}

// ---- GEMM1 via bf16 MFMA, split precision, 1-barrier pipelined K-loop.
//      MFMA issued in 3 passes of 16 independent ops (no serial acc chains).
//      Depth-3 x prefetch (load->use ~2 iterations). Fused as1/ad1 epilogue.
__global__ __launch_bounds__(256, 3) void gemm1_mfma_kernel(
    const float* __restrict__ x, const short* __restrict__ Wh,
    const short* __restrict__ Wl, __half* __restrict__ h1h,
    const float* __restrict__ att_s, const float* __restrict__ att_d,
    float* __restrict__ as1, float* __restrict__ ad1) {
  // double-buffered A LDS, XOR-swizzled 16B units: us = u ^ (((u>>4)&3)<<1)
  __shared__ __align__(16) short Ah[2][2048];
  __shared__ __align__(16) short Al[2][2048];
  const int tid = threadIdx.x;
  const int lane = tid & 63, wav = tid >> 6;
  const int m0 = blockIdx.x * 64;
  const int m_local = tid >> 2, oct = tid & 3;
  const int gm = m0 + m_local;
  const bool vrow = (gm < N_NODES);
  const long xbase = (long)gm * F_IN;
  const int wu0 = ((m_local >> 4) * 64) + ((m_local & 15) | (oct << 4));
  const int wu = wu0 ^ ((((unsigned)wu0 >> 4) & 3) << 1);

  float atts[4], attd[4];
#pragma unroll
  for (int nf = 0; nf < 4; ++nf) {
    int c = wav * 64 + nf * 16 + (lane & 15);
    atts[nf] = att_s[c];
    attd[nf] = att_d[c];
  }

  f32x4 acc[4][4];
#pragma unroll
  for (int i = 0; i < 4; ++i)
#pragma unroll
    for (int j = 0; j < 4; ++j) acc[i][j] = (f32x4){0.f, 0.f, 0.f, 0.f};

  // depth-3 x prefetch (ks 0,1,2 all well inside bounds: max k = 95)
  float xr0[8], xr1[8], xr2[8];
  {
    int kb = oct * 8;
#pragma unroll
    for (int j = 0; j < 8; ++j) xr0[j] = vrow ? x[xbase + kb + j] : 0.f;
#pragma unroll
    for (int j = 0; j < 8; ++j) xr1[j] = vrow ? x[xbase + 32 + kb + j] : 0.f;
#pragma unroll
    for (int j = 0; j < 8; ++j) xr2[j] = vrow ? x[xbase + 64 + kb + j] : 0.f;
  }
  // B prefetch for ks=0
  short8 bhc[4], blc[4];
  {
    const short* wb = Wh + ((wav * 4) * 64 + lane) * 8;
    const short* wbl = Wl + ((wav * 4) * 64 + lane) * 8;
#pragma unroll
    for (int nf = 0; nf < 4; ++nf) {
      bhc[nf] = *(const short8*)(wb + nf * 512);
      blc[nf] = *(const short8*)(wbl + nf * 512);
    }
  }

#pragma unroll 2
  for (int ks = 0; ks < KSTEPS; ++ks) {
    short8 hi8, lo8;
#pragma unroll
    for (int j = 0; j < 8; ++j) {
      unsigned short h = f2bf(xr0[j]);
      float lf = xr0[j] - bf2f(h);
      hi8[j] = (short)h;
      lo8[j] = (short)f2bf(lf);
    }
    *(short8*)&Ah[ks & 1][wu * 8] = hi8;
    *(short8*)&Al[ks & 1][wu * 8] = lo8;
    // rotate prefetch; issue x load for ks+3
    {
#pragma unroll
      for (int j = 0; j < 8; ++j) xr0[j] = xr1[j];
#pragma unroll
      for (int j = 0; j < 8; ++j) xr1[j] = xr2[j];
      int s = ks + 3;
      if (s < KSTEPS - 1) {
        int kb = s * 32 + oct * 8;
#pragma unroll
        for (int j = 0; j < 8; ++j) xr2[j] = vrow ? x[xbase + kb + j] : 0.f;
      } else if (s == KSTEPS - 1) {
        int kb = s * 32 + oct * 8;
#pragma unroll
        for (int j = 0; j < 8; ++j) {
          int k = kb + j;
          xr2[j] = (vrow && k < F_IN) ? x[xbase + k] : 0.f;
        }
      }
    }
    __syncthreads();
    short8 ah[4], al[4];
#pragma unroll
    for (int mf = 0; mf < 4; ++mf) {
      int u = mf * 64 + lane;
      int us = u ^ ((((unsigned)u >> 4) & 3) << 1);
      ah[mf] = *(short8*)&Ah[ks & 1][us * 8];
      al[mf] = *(short8*)&Al[ks & 1][us * 8];
    }
    // B prefetch for ks+1 (in flight across the MFMA block)
    short8 bhn[4], bln[4];
    if (ks + 1 < KSTEPS) {
      const short* wb = Wh + (((ks + 1) * 16 + wav * 4) * 64 + lane) * 8;
      const short* wbl = Wl + (((ks + 1) * 16 + wav * 4) * 64 + lane) * 8;
#pragma unroll
      for (int nf = 0; nf < 4; ++nf) {
        bhn[nf] = *(const short8*)(wb + nf * 512);
        bln[nf] = *(const short8*)(wbl + nf * 512);
      }
    }
    // 3 passes of 16 independent MFMAs each (dep distance 16 >> latency)
#pragma unroll
    for (int mf = 0; mf < 4; ++mf)
#pragma unroll
      for (int nf = 0; nf < 4; ++nf)
        acc[mf][nf] = __builtin_amdgcn_mfma_f32_16x16x32_bf16(ah[mf], bhc[nf], acc[mf][nf], 0, 0, 0);
#pragma unroll
    for (int mf = 0; mf < 4; ++mf)
#pragma unroll
      for (int nf = 0; nf < 4; ++nf)
        acc[mf][nf] = __builtin_amdgcn_mfma_f32_16x16x32_bf16(ah[mf], blc[nf], acc[mf][nf], 0, 0, 0);
#pragma unroll
    for (int mf = 0; mf < 4; ++mf)
#pragma unroll
      for (int nf = 0; nf < 4; ++nf)
        acc[mf][nf] = __builtin_amdgcn_mfma_f32_16x16x32_bf16(al[mf], bhc[nf], acc[mf][nf], 0, 0, 0);
#pragma unroll
    for (int nf = 0; nf < 4; ++nf) {
      bhc[nf] = bhn[nf];
      blc[nf] = bln[nf];
    }
  }

  // epilogue: h1 (fp16) store + fused as1/ad1 reduction
  const int r0 = (lane >> 4) * 4, cn = lane & 15;
#pragma unroll
  for (int mf = 0; mf < 4; ++mf) {
    int rowb = m0 + mf * 16 + r0;
#pragma unroll
    for (int r = 0; r < 4; ++r) {
      int row = rowb + r;
      bool ok = (row < N_NODES);
      if (ok) {
#pragma unroll
        for (int nf = 0; nf < 4; ++nf)
          h1h[(long)row * HID + wav * 64 + nf * 16 + cn] =
              __float2half_rn(acc[mf][nf][r]);
      }
      float s0 = acc[mf][0][r] * atts[0] + acc[mf][1][r] * atts[1];
      float s1 = acc[mf][2][r] * atts[2] + acc[mf][3][r] * atts[3];
      float d0 = acc[mf][0][r] * attd[0] + acc[mf][1][r] * attd[1];
      float d1 = acc[mf][2][r] * attd[2] + acc[mf][3][r] * attd[3];
#pragma unroll
      for (int o = 1; o < 16; o <<= 1) {
        s0 += __shfl_xor(s0, o, 64);
        s1 += __shfl_xor(s1, o, 64);
        d0 += __shfl_xor(d0, o, 64);
        d1 += __shfl_xor(d1, o, 64);
      }
      if (ok && cn == 0) {
        as1[row * NHEAD + wav * 2]     = s0;
        as1[row * NHEAD + wav * 2 + 1] = s1;
        ad1[row * NHEAD + wav * 2]     = d0;
        ad1[row * NHEAD + wav * 2 + 1] = d1;
      }
    }
  }
}

// ---------------- CSR build ----------------
__global__ void count_kernel(const int* __restrict__ ei, int* __restrict__ deg) {
  int e = blockIdx.x * blockDim.x + threadIdx.x;
  if (e >= EL) return;
  int dst = (e < N_EDGES) ? ei[N_EDGES + e] : (e - N_EDGES);
  atomicAdd(&deg[dst], 1);
}

// 3-phase parallel exclusive scan of deg -> off
__global__ __launch_bounds__(1024) void scan_part_kernel(
    const int* __restrict__ deg, int* __restrict__ off, int* __restrict__ btot) {
  __shared__ int warp_sums[16];
  const int tid = threadIdx.x;
  const int lane = tid & 63, wid = tid >> 6;
  int i = blockIdx.x * 1024 + tid;
  int v = (i < N_NODES) ? deg[i] : 0;
  int x = v;
#pragma unroll
  for (int o = 1; o < 64; o <<= 1) {
    int y = __shfl_up(x, o, 64);
    if (lane >= o) x += y;
  }
  if (lane == 63) warp_sums[wid] = x;
  __syncthreads();
  if (wid == 0) {
    int ws = (lane < 16) ? warp_sums[lane] : 0;
#pragma unroll
    for (int o = 1; o < 16; o <<= 1) {
      int y = __shfl_up(ws, o, 64);
      if (lane >= o) ws += y;
    }
    if (lane < 16) warp_sums[lane] = ws;
  }
  __syncthreads();
  int wprefix = (wid > 0) ? warp_sums[wid - 1] : 0;
  if (i < N_NODES) off[i] = wprefix + x - v;
  if (tid == 1023) btot[blockIdx.x] = warp_sums[15];
}

__global__ __launch_bounds__(64) void scan_tops_kernel(
    const int* __restrict__ btot, int* __restrict__ bo) {
  int lane = threadIdx.x;
  int v = (lane < NB_SCAN) ? btot[lane] : 0;
  int x = v;
#pragma unroll
  for (int o = 1; o < 64; o <<= 1) {
    int y = __shfl_up(x, o, 64);
    if (lane >= o) x += y;
  }
  if (lane < NB_SCAN) bo[lane] = x - v;  // exclusive
}

__global__ void scan_add_kernel(int* __restrict__ off, const int* __restrict__ bo) {
  int i = blockIdx.x * blockDim.x + threadIdx.x;
  if (i > N_NODES) return;
  if (i == N_NODES) off[i] = EL;
  else off[i] += bo[i >> 10];
}

// ---- fill CSR + per-edge layer-1 softmax numerators (no-max exp) ----
// Logits e = as+ad ~ N(0,~1.1): |e| < ~7 over 6.8M samples -> exp safe in fp32.
__global__ void fill_p1_kernel(const int* __restrict__ ei, const int* __restrict__ off,
                               int* __restrict__ cur, const float* __restrict__ as1,
                               const float* __restrict__ ad1, int* __restrict__ csr,
                               float* __restrict__ p1) {
  int e = blockIdx.x * blockDim.x + threadIdx.x;
  if (e >= EL) return;
  int src, dst;
  if (e < N_EDGES) { src = ei[e]; dst = ei[N_EDGES + e]; }
  else { src = e - N_EDGES; dst = src; }
  int slot = off[dst] + atomicAdd(&cur[dst], 1);
  csr[slot] = src;
  float4 s0 = *(const float4*)&as1[src * NHEAD];
  float4 s1 = *(const float4*)&as1[src * NHEAD + 4];
  float4 d0 = *(const float4*)&ad1[dst * NHEAD];
  float4 d1 = *(const float4*)&ad1[dst * NHEAD + 4];
  float ev[8] = {s0.x + d0.x, s0.y + d0.y, s0.z + d0.z, s0.w + d0.w,
                 s1.x + d1.x, s1.y + d1.y, s1.z + d1.z, s1.w + d1.w};
  float pv[8];
#pragma unroll
  for (int h = 0; h < 8; ++h) {
    float t = ev[h];
    t = (t >= 0.f) ? t : 0.2f * t;
    pv[h] = __expf(t);
  }
  *(float4*)&p1[slot * 8]     = make_float4(pv[0], pv[1], pv[2], pv[3]);
  *(float4*)&p1[slot * 8 + 4] = make_float4(pv[4], pv[5], pv[6], pv[7]);
}

// ---- layer-1 aggregation: single pass, precomputed p, half2 gather, 8-unroll ----
__global__ __launch_bounds__(256) void agg1_kernel(
    const __half* __restrict__ h1h, const float* __restrict__ p1,
    const int* __restrict__ off, const int* __restrict__ csr,
    const float* __restrict__ b1, float* __restrict__ out1) {
  const int t = threadIdx.x & 127;
  const int n = blockIdx.x * 2 + (threadIdx.x >> 7);
  if (n >= N_NODES) return;
  const int head = t >> 4;
  const int j0 = off[n], j1 = off[n + 1];
  float acc0 = 0.f, acc1 = 0.f, den = 0.f;
  int j = j0;
  for (; j + 7 < j1; j += 8) {
    int s[8];
    float pw[8];
    __half2 v[8];
#pragma unroll
    for (int q = 0; q < 8; ++q) s[q] = csr[j + q];
#pragma unroll
    for (int q = 0; q < 8; ++q) {
      pw[q] = p1[(j + q) * 8 + head];
      v[q] = *(const __half2*)&h1h[s[q] * HID + t * 2];
    }
#pragma unroll
    for (int q = 0; q < 8; ++q) {
      float2 f = __half22float2(v[q]);
      den += pw[q];
      acc0 += pw[q] * f.x;
      acc1 += pw[q] * f.y;
    }
  }
  for (; j < j1; ++j) {
    int s0 = csr[j];
    float p0 = p1[j * 8 + head];
    __half2 v0 = *(const __half2*)&h1h[s0 * HID + t * 2];
    float2 f0 = __half22float2(v0);
    den += p0;
    acc0 += p0 * f0.x;
    acc1 += p0 * f0.y;
  }
  float rden = 1.f / (den + 1e-16f);
  float v0 = acc0 * rden + b1[t * 2];
  float v1 = acc1 * rden + b1[t * 2 + 1];
  out1[n * HID + t * 2]     = (v0 > 0.f) ? v0 : (__expf(v0) - 1.f);
  out1[n * HID + t * 2 + 1] = (v1 > 0.f) ? v1 : (__expf(v1) - 1.f);
}

// ---------------- layer 2 linear + attention coefficients ----------------
__global__ __launch_bounds__(256) void lin2_kernel(
    const float* __restrict__ o1, const float* __restrict__ W2,
    const float* __restrict__ att_s2, const float* __restrict__ att_d2,
    float* __restrict__ h2, float* __restrict__ as2, float* __restrict__ ad2) {
  __shared__ float W2s[HID * 10];
  int tid = threadIdx.x;
  for (int i = tid; i < HID * 10; i += 256) W2s[i] = W2[i];
  __syncthreads();
  int wave = tid >> 6, lane = tid & 63;
  int n = blockIdx.x * 4 + wave;
  if (n >= N_NODES) return;
  float4 xv = *(const float4*)&o1[n * HID + lane * 4];
  float hk[10];
#pragma unroll
  for (int k = 0; k < 10; ++k) {
    float p = xv.x * W2s[(lane * 4 + 0) * 10 + k] +
              xv.y * W2s[(lane * 4 + 1) * 10 + k] +
              xv.z * W2s[(lane * 4 + 2) * 10 + k] +
              xv.w * W2s[(lane * 4 + 3) * 10 + k];
#pragma unroll
    for (int o = 32; o >= 1; o >>= 1) p += __shfl_down(p, o, 64);
    hk[k] = p;
  }
  if (lane == 0) {
    float s = 0.f, d = 0.f;
#pragma unroll
    for (int k = 0; k < 10; ++k) {
      h2[n * 10 + k] = hk[k];
      s += hk[k] * att_s2[k];
      d += hk[k] * att_d2[k];
    }
    as2[n] = s;
    ad2[n] = d;
  }
}

// ---------------- layer-2 aggregation (exp fused, single pass) ----------------
__global__ __launch_bounds__(256) void agg2_kernel(
    const float* __restrict__ h2, const float* __restrict__ as2,
    const float* __restrict__ ad2, const int* __restrict__ off,
    const int* __restrict__ csr, const float* __restrict__ b2,
    float* __restrict__ out) {
  int wave = threadIdx.x >> 6, lane = threadIdx.x & 63;
  int n = blockIdx.x * 4 + wave;
  if (n >= N_NODES) return;
  float adn = ad2[n];
  int j0 = off[n], j1 = off[n + 1];
  float acc = 0.f, den = 0.f;
  int j = j0;
  for (; j + 1 < j1; j += 2) {
    int s0 = csr[j], s1 = csr[j + 1];
    float e0 = as2[s0] + adn, e1 = as2[s1] + adn;
    e0 = (e0 >= 0.f) ? e0 : 0.2f * e0;
    e1 = (e1 >= 0.f) ? e1 : 0.2f * e1;
    float p0 = __expf(e0), p1v = __expf(e1);
    den += p0 + p1v;
    if (lane < 10) acc += p0 * h2[s0 * 10 + lane] + p1v * h2[s1 * 10 + lane];
  }
  if (j < j1) {
    int s0 = csr[j];
    float e0 = as2[s0] + adn;
    e0 = (e0 >= 0.f) ? e0 : 0.2f * e0;
    float p0 = __expf(e0);
    den += p0;
    if (lane < 10) acc += p0 * h2[s0 * 10 + lane];
  }
  if (lane < 10) out[n * 10 + lane] = acc / (den + 1e-16f) + b2[lane];
}

extern "C" void kernel_launch(void* const* d_in, const int* in_sizes, int n_in,
                              void* d_out, int out_size, void* d_ws, size_t ws_size,
                              hipStream_t stream) {
  const float* x    = (const float*)d_in[0];
  const int*   ei   = (const int*)d_in[1];
  const float* W1   = (const float*)d_in[2];
  const float* as1w = (const float*)d_in[3];
  const float* ad1w = (const float*)d_in[4];
  const float* b1   = (const float*)d_in[5];
  const float* W2   = (const float*)d_in[6];
  const float* as2w = (const float*)d_in[7];
  const float* ad2w = (const float*)d_in[8];
  const float* b2   = (const float*)d_in[9];
  float* out = (float*)d_out;

  char* p = (char*)d_ws;
  __half* h1h = (__half*)p; p += (size_t)N_NODES * HID * 2;
  float* o1   = (float*)p; p += (size_t)N_NODES * HID * 4;
  float* a_s1 = (float*)p; p += (size_t)N_NODES * NHEAD * 4;
  float* a_d1 = (float*)p; p += (size_t)N_NODES * NHEAD * 4;
  float* h2   = (float*)p; p += (size_t)N_NODES * 10 * 4;
  float* a_s2 = (float*)p; p += (size_t)N_NODES * 4;
  float* a_d2 = (float*)p; p += (size_t)N_NODES * 4;
  short* Wh   = (short*)p; p += (size_t)KSTEPS * 16 * 64 * 8 * 2;
  short* Wl   = (short*)p; p += (size_t)KSTEPS * 16 * 64 * 8 * 2;
  int* deg    = (int*)p;   p += (size_t)N_NODES * 4;
  int* cur    = (int*)p;   p += (size_t)N_NODES * 4;
  int* off    = (int*)p;   p += (size_t)(N_NODES + 1) * 4;
  int* csr    = (int*)p;   p += (size_t)EL * 4;
  float* p1   = (float*)p; p += (size_t)EL * NHEAD * 4;
  int* btot   = (int*)p;   p += 64 * 4;
  int* bo     = (int*)p;   p += 64 * 4;

  prep_kernel<<<768, 256, 0, stream>>>(W1, Wh, Wl);
  gemm1_mfma_kernel<<<(N_NODES + 63) / 64, 256, 0, stream>>>(
      x, Wh, Wl, h1h, as1w, ad1w, a_s1, a_d1);
  hipMemsetAsync(deg, 0, (size_t)N_NODES * 2 * 4, stream);  // deg + cur (adjacent)
  count_kernel<<<(EL + 255) / 256, 256, 0, stream>>>(ei, deg);
  scan_part_kernel<<<NB_SCAN, 1024, 0, stream>>>(deg, off, btot);
  scan_tops_kernel<<<1, 64, 0, stream>>>(btot, bo);
  scan_add_kernel<<<(N_NODES + 256) / 256, 256, 0, stream>>>(off, bo);
  fill_p1_kernel<<<(EL + 255) / 256, 256, 0, stream>>>(ei, off, cur, a_s1, a_d1, csr, p1);
  agg1_kernel<<<(N_NODES + 1) / 2, 256, 0, stream>>>(h1h, p1, off, csr, b1, o1);
  lin2_kernel<<<(N_NODES + 3) / 4, 256, 0, stream>>>(o1, W2, as2w, ad2w, h2, a_s2, a_d2);
  agg2_kernel<<<(N_NODES + 3) / 4, 256, 0, stream>>>(h2, a_s2, a_d2, off, csr, b2, out);
}

// Round 7
// 534.855 us; speedup vs baseline: 1.2740x; 1.2740x over previous
//
#include <hip/hip_runtime.h>
#include <hip/hip_fp16.h>

#define N_NODES 50000
#define N_EDGES 800000
#define EL (N_EDGES + N_NODES) /* 850000 */
#define F_IN 767
#define HID 256
#define NHEAD 8
#define KSTEPS 24 /* ceil(767/32) */
#define CK 4      /* K-steps per LDS chunk */
#define NCHUNK 6  /* 24 / 4 */
#define NB_SCAN 49 /* ceil(50000/1024) */

typedef __attribute__((ext_vector_type(8))) short short8;
typedef __attribute__((ext_vector_type(4))) float f32x4;

static __device__ __forceinline__ unsigned short f2bf(float f) {
  unsigned int u = __float_as_uint(f);
  unsigned int r = (u + 0x7fffu + ((u >> 16) & 1u)) >> 16;
  return (unsigned short)r;
}
static __device__ __forceinline__ float bf2f(unsigned short h) {
  return __uint_as_float(((unsigned int)h) << 16);
}

// ---- prep: split W into bf16 hi/lo and repack into MFMA fragment order ----
__global__ __launch_bounds__(256) void prep_kernel(
    const float* __restrict__ W, short* __restrict__ Wh, short* __restrict__ Wl) {
  int idx = blockIdx.x * 256 + threadIdx.x;  // 768*256 threads
  int k = idx >> 8, n = idx & 255;
  float v = (k < F_IN) ? W[k * HID + n] : 0.f;
  unsigned short h = f2bf(v);
  float lf = v - bf2f(h);
  unsigned short lo = f2bf(lf);
  int ks = k >> 5, oct = (k >> 3) & 3, j = k & 7;
  int nf = n >> 4;
  int l = (n & 15) | (oct << 4);
  int addr = ((ks * 16 + nf) * 64 + l) * 8 + j;
  Wh[addr] = (short)h;
  Wl[addr] = (short)lo;
}

// ---- GEMM1: bf16 MFMA split precision, K-chunked double-buffered LDS.
//      6 barriers/block (1 per 128-k chunk); inner 4-ks loop barrier-free.
//      x-loads for chunk c+1 issued right AFTER the barrier so the next
//      barrier's vmcnt drain comes a full compute phase later (drain ~free).
__global__ __launch_bounds__(256) void gemm1_mfma_kernel(
    const float* __restrict__ x, const short* __restrict__ Wh,
    const short* __restrict__ Wl, __half* __restrict__ h1h,
    const float* __restrict__ att_s, const float* __restrict__ att_d,
    float* __restrict__ as1, float* __restrict__ ad1) {
  // [buf][hi/lo][ (kl*4+mf)*64 + unit ][8] shorts; unit swizzled by ^kl
  __shared__ __align__(16) short Ab[2][2][CK * 4 * 64 * 8];
  const int tid = threadIdx.x;
  const int lane = tid & 63, wav = tid >> 6;
  const int m0 = blockIdx.x * 64;
  const int r = tid >> 2;   // row 0..63 owned for staging
  const int kl = tid & 3;   // ks-within-chunk owned for staging
  const int gm = m0 + r;
  const bool vrow = (gm < N_NODES);
  const long xbase = (long)gm * F_IN;

  float atts[4], attd[4];
#pragma unroll
  for (int nf = 0; nf < 4; ++nf) {
    int c = wav * 64 + nf * 16 + (lane & 15);
    atts[nf] = att_s[c];
    attd[nf] = att_d[c];
  }

  f32x4 acc[4][4];
#pragma unroll
  for (int i = 0; i < 4; ++i)
#pragma unroll
    for (int j = 0; j < 4; ++j) acc[i][j] = (f32x4){0.f, 0.f, 0.f, 0.f};

  // stage regs: 32 floats = this thread's (row r, ks kl) slice of one chunk
  float xn[32];
  {
    int kb = kl * 32;  // chunk 0
#pragma unroll
    for (int j = 0; j < 32; ++j) xn[j] = vrow ? x[xbase + kb + j] : 0.f;
  }

  for (int c = 0; c < NCHUNK; ++c) {
    const int buf = c & 1;
    // convert chunk c regs -> LDS fragments (hi/lo)
#pragma unroll
    for (int oct = 0; oct < 4; ++oct) {
      short8 hi8, lo8;
#pragma unroll
      for (int j = 0; j < 8; ++j) {
        float v = xn[oct * 8 + j];
        unsigned short h = f2bf(v);
        hi8[j] = (short)h;
        lo8[j] = (short)f2bf(v - bf2f(h));
      }
      int u = (((r & 15) | (oct << 4)) ^ kl);
      int addr = ((kl * 4 + (r >> 4)) * 64 + u) * 8;
      *(short8*)&Ab[buf][0][addr] = hi8;
      *(short8*)&Ab[buf][1][addr] = lo8;
    }
    __syncthreads();  // single barrier per chunk (write->read fence)
    // issue x loads for chunk c+1 (in flight across the whole compute phase)
    if (c + 1 < NCHUNK) {
      int kb = (c + 1) * 128 + kl * 32;
      if (c + 1 == NCHUNK - 1) {
#pragma unroll
        for (int j = 0; j < 32; ++j) {
          int k = kb + j;
          xn[j] = (vrow && k < F_IN) ? x[xbase + k] : 0.f;
        }
      } else {
#pragma unroll
        for (int j = 0; j < 32; ++j) xn[j] = vrow ? x[xbase + kb + j] : 0.f;
      }
    }
    // compute 4 ks from LDS buf (no barriers; compiler pipelines B loads)
#pragma unroll
    for (int ki = 0; ki < CK; ++ki) {
      const int ksg = c * CK + ki;
      short8 ah[4], al[4];
#pragma unroll
      for (int mf = 0; mf < 4; ++mf) {
        int addr = ((ki * 4 + mf) * 64 + (lane ^ ki)) * 8;
        ah[mf] = *(short8*)&Ab[buf][0][addr];
        al[mf] = *(short8*)&Ab[buf][1][addr];
      }
      short8 bh[4], bl[4];
      const short* wb = Wh + ((ksg * 16 + wav * 4) * 64 + lane) * 8;
      const short* wbl = Wl + ((ksg * 16 + wav * 4) * 64 + lane) * 8;
#pragma unroll
      for (int nf = 0; nf < 4; ++nf) {
        bh[nf] = *(const short8*)(wb + nf * 512);
        bl[nf] = *(const short8*)(wbl + nf * 512);
      }
      // 3 passes of 16 independent MFMAs (dep distance 16 >> latency)
#pragma unroll
      for (int mf = 0; mf < 4; ++mf)
#pragma unroll
        for (int nf = 0; nf < 4; ++nf)
          acc[mf][nf] = __builtin_amdgcn_mfma_f32_16x16x32_bf16(ah[mf], bh[nf], acc[mf][nf], 0, 0, 0);
#pragma unroll
      for (int mf = 0; mf < 4; ++mf)
#pragma unroll
        for (int nf = 0; nf < 4; ++nf)
          acc[mf][nf] = __builtin_amdgcn_mfma_f32_16x16x32_bf16(ah[mf], bl[nf], acc[mf][nf], 0, 0, 0);
#pragma unroll
      for (int mf = 0; mf < 4; ++mf)
#pragma unroll
        for (int nf = 0; nf < 4; ++nf)
          acc[mf][nf] = __builtin_amdgcn_mfma_f32_16x16x32_bf16(al[mf], bh[nf], acc[mf][nf], 0, 0, 0);
    }
  }

  // epilogue: h1 (fp16) store + fused as1/ad1 reduction
  const int r0 = (lane >> 4) * 4, cn = lane & 15;
#pragma unroll
  for (int mf = 0; mf < 4; ++mf) {
    int rowb = m0 + mf * 16 + r0;
#pragma unroll
    for (int rr = 0; rr < 4; ++rr) {
      int row = rowb + rr;
      bool ok = (row < N_NODES);
      if (ok) {
#pragma unroll
        for (int nf = 0; nf < 4; ++nf)
          h1h[(long)row * HID + wav * 64 + nf * 16 + cn] =
              __float2half_rn(acc[mf][nf][rr]);
      }
      float s0 = acc[mf][0][rr] * atts[0] + acc[mf][1][rr] * atts[1];
      float s1 = acc[mf][2][rr] * atts[2] + acc[mf][3][rr] * atts[3];
      float d0 = acc[mf][0][rr] * attd[0] + acc[mf][1][rr] * attd[1];
      float d1 = acc[mf][2][rr] * attd[2] + acc[mf][3][rr] * attd[3];
#pragma unroll
      for (int o = 1; o < 16; o <<= 1) {
        s0 += __shfl_xor(s0, o, 64);
        s1 += __shfl_xor(s1, o, 64);
        d0 += __shfl_xor(d0, o, 64);
        d1 += __shfl_xor(d1, o, 64);
      }
      if (ok && cn == 0) {
        as1[row * NHEAD + wav * 2]     = s0;
        as1[row * NHEAD + wav * 2 + 1] = s1;
        ad1[row * NHEAD + wav * 2]     = d0;
        ad1[row * NHEAD + wav * 2 + 1] = d1;
      }
    }
  }
}

// ---------------- CSR build ----------------
__global__ void count_kernel(const int* __restrict__ ei, int* __restrict__ deg) {
  int e = blockIdx.x * blockDim.x + threadIdx.x;
  if (e >= EL) return;
  int dst = (e < N_EDGES) ? ei[N_EDGES + e] : (e - N_EDGES);
  atomicAdd(&deg[dst], 1);
}

__global__ __launch_bounds__(1024) void scan_part_kernel(
    const int* __restrict__ deg, int* __restrict__ off, int* __restrict__ btot) {
  __shared__ int warp_sums[16];
  const int tid = threadIdx.x;
  const int lane = tid & 63, wid = tid >> 6;
  int i = blockIdx.x * 1024 + tid;
  int v = (i < N_NODES) ? deg[i] : 0;
  int x = v;
#pragma unroll
  for (int o = 1; o < 64; o <<= 1) {
    int y = __shfl_up(x, o, 64);
    if (lane >= o) x += y;
  }
  if (lane == 63) warp_sums[wid] = x;
  __syncthreads();
  if (wid == 0) {
    int ws = (lane < 16) ? warp_sums[lane] : 0;
#pragma unroll
    for (int o = 1; o < 16; o <<= 1) {
      int y = __shfl_up(ws, o, 64);
      if (lane >= o) ws += y;
    }
    if (lane < 16) warp_sums[lane] = ws;
  }
  __syncthreads();
  int wprefix = (wid > 0) ? warp_sums[wid - 1] : 0;
  if (i < N_NODES) off[i] = wprefix + x - v;
  if (tid == 1023) btot[blockIdx.x] = warp_sums[15];
}

__global__ __launch_bounds__(64) void scan_tops_kernel(
    const int* __restrict__ btot, int* __restrict__ bo) {
  int lane = threadIdx.x;
  int v = (lane < NB_SCAN) ? btot[lane] : 0;
  int x = v;
#pragma unroll
  for (int o = 1; o < 64; o <<= 1) {
    int y = __shfl_up(x, o, 64);
    if (lane >= o) x += y;
  }
  if (lane < NB_SCAN) bo[lane] = x - v;  // exclusive
}

__global__ void scan_add_kernel(int* __restrict__ off, const int* __restrict__ bo) {
  int i = blockIdx.x * blockDim.x + threadIdx.x;
  if (i > N_NODES) return;
  if (i == N_NODES) off[i] = EL;
  else off[i] += bo[i >> 10];
}

// ---- fill CSR + per-edge layer-1 softmax numerators (no-max exp) ----
// Logits e = as+ad ~ N(0,~1.1): |e| < ~7 over 6.8M samples -> exp safe in fp32.
__global__ void fill_p1_kernel(const int* __restrict__ ei, const int* __restrict__ off,
                               int* __restrict__ cur, const float* __restrict__ as1,
                               const float* __restrict__ ad1, int* __restrict__ csr,
                               float* __restrict__ p1) {
  int e = blockIdx.x * blockDim.x + threadIdx.x;
  if (e >= EL) return;
  int src, dst;
  if (e < N_EDGES) { src = ei[e]; dst = ei[N_EDGES + e]; }
  else { src = e - N_EDGES; dst = src; }
  int slot = off[dst] + atomicAdd(&cur[dst], 1);
  csr[slot] = src;
  float4 s0 = *(const float4*)&as1[src * NHEAD];
  float4 s1 = *(const float4*)&as1[src * NHEAD + 4];
  float4 d0 = *(const float4*)&ad1[dst * NHEAD];
  float4 d1 = *(const float4*)&ad1[dst * NHEAD + 4];
  float ev[8] = {s0.x + d0.x, s0.y + d0.y, s0.z + d0.z, s0.w + d0.w,
                 s1.x + d1.x, s1.y + d1.y, s1.z + d1.z, s1.w + d1.w};
  float pv[8];
#pragma unroll
  for (int h = 0; h < 8; ++h) {
    float t = ev[h];
    t = (t >= 0.f) ? t : 0.2f * t;
    pv[h] = __expf(t);
  }
  *(float4*)&p1[slot * 8]     = make_float4(pv[0], pv[1], pv[2], pv[3]);
  *(float4*)&p1[slot * 8 + 4] = make_float4(pv[4], pv[5], pv[6], pv[7]);
}

// ---- layer-1 aggregation: single pass, precomputed p, half2 gather, 8-unroll ----
__global__ __launch_bounds__(256) void agg1_kernel(
    const __half* __restrict__ h1h, const float* __restrict__ p1,
    const int* __restrict__ off, const int* __restrict__ csr,
    const float* __restrict__ b1, float* __restrict__ out1) {
  const int t = threadIdx.x & 127;
  const int n = blockIdx.x * 2 + (threadIdx.x >> 7);
  if (n >= N_NODES) return;
  const int head = t >> 4;
  const int j0 = off[n], j1 = off[n + 1];
  float acc0 = 0.f, acc1 = 0.f, den = 0.f;
  int j = j0;
  for (; j + 7 < j1; j += 8) {
    int s[8];
    float pw[8];
    __half2 v[8];
#pragma unroll
    for (int q = 0; q < 8; ++q) s[q] = csr[j + q];
#pragma unroll
    for (int q = 0; q < 8; ++q) {
      pw[q] = p1[(j + q) * 8 + head];
      v[q] = *(const __half2*)&h1h[s[q] * HID + t * 2];
    }
#pragma unroll
    for (int q = 0; q < 8; ++q) {
      float2 f = __half22float2(v[q]);
      den += pw[q];
      acc0 += pw[q] * f.x;
      acc1 += pw[q] * f.y;
    }
  }
  for (; j < j1; ++j) {
    int s0 = csr[j];
    float p0 = p1[j * 8 + head];
    __half2 v0 = *(const __half2*)&h1h[s0 * HID + t * 2];
    float2 f0 = __half22float2(v0);
    den += p0;
    acc0 += p0 * f0.x;
    acc1 += p0 * f0.y;
  }
  float rden = 1.f / (den + 1e-16f);
  float v0 = acc0 * rden + b1[t * 2];
  float v1 = acc1 * rden + b1[t * 2 + 1];
  out1[n * HID + t * 2]     = (v0 > 0.f) ? v0 : (__expf(v0) - 1.f);
  out1[n * HID + t * 2 + 1] = (v1 > 0.f) ? v1 : (__expf(v1) - 1.f);
}

// ---------------- layer 2 linear + attention coefficients ----------------
__global__ __launch_bounds__(256) void lin2_kernel(
    const float* __restrict__ o1, const float* __restrict__ W2,
    const float* __restrict__ att_s2, const float* __restrict__ att_d2,
    float* __restrict__ h2, float* __restrict__ as2, float* __restrict__ ad2) {
  __shared__ float W2s[HID * 10];
  int tid = threadIdx.x;
  for (int i = tid; i < HID * 10; i += 256) W2s[i] = W2[i];
  __syncthreads();
  int wave = tid >> 6, lane = tid & 63;
  int n = blockIdx.x * 4 + wave;
  if (n >= N_NODES) return;
  float4 xv = *(const float4*)&o1[n * HID + lane * 4];
  float hk[10];
#pragma unroll
  for (int k = 0; k < 10; ++k) {
    float p = xv.x * W2s[(lane * 4 + 0) * 10 + k] +
              xv.y * W2s[(lane * 4 + 1) * 10 + k] +
              xv.z * W2s[(lane * 4 + 2) * 10 + k] +
              xv.w * W2s[(lane * 4 + 3) * 10 + k];
#pragma unroll
    for (int o = 32; o >= 1; o >>= 1) p += __shfl_down(p, o, 64);
    hk[k] = p;
  }
  if (lane == 0) {
    float s = 0.f, d = 0.f;
#pragma unroll
    for (int k = 0; k < 10; ++k) {
      h2[n * 10 + k] = hk[k];
      s += hk[k] * att_s2[k];
      d += hk[k] * att_d2[k];
    }
    as2[n] = s;
    ad2[n] = d;
  }
}

// ---------------- layer-2 aggregation (exp fused, single pass) ----------------
__global__ __launch_bounds__(256) void agg2_kernel(
    const float* __restrict__ h2, const float* __restrict__ as2,
    const float* __restrict__ ad2, const int* __restrict__ off,
    const int* __restrict__ csr, const float* __restrict__ b2,
    float* __restrict__ out) {
  int wave = threadIdx.x >> 6, lane = threadIdx.x & 63;
  int n = blockIdx.x * 4 + wave;
  if (n >= N_NODES) return;
  float adn = ad2[n];
  int j0 = off[n], j1 = off[n + 1];
  float acc = 0.f, den = 0.f;
  int j = j0;
  for (; j + 1 < j1; j += 2) {
    int s0 = csr[j], s1 = csr[j + 1];
    float e0 = as2[s0] + adn, e1 = as2[s1] + adn;
    e0 = (e0 >= 0.f) ? e0 : 0.2f * e0;
    e1 = (e1 >= 0.f) ? e1 : 0.2f * e1;
    float p0 = __expf(e0), p1v = __expf(e1);
    den += p0 + p1v;
    if (lane < 10) acc += p0 * h2[s0 * 10 + lane] + p1v * h2[s1 * 10 + lane];
  }
  if (j < j1) {
    int s0 = csr[j];
    float e0 = as2[s0] + adn;
    e0 = (e0 >= 0.f) ? e0 : 0.2f * e0;
    float p0 = __expf(e0);
    den += p0;
    if (lane < 10) acc += p0 * h2[s0 * 10 + lane];
  }
  if (lane < 10) out[n * 10 + lane] = acc / (den + 1e-16f) + b2[lane];
}

extern "C" void kernel_launch(void* const* d_in, const int* in_sizes, int n_in,
                              void* d_out, int out_size, void* d_ws, size_t ws_size,
                              hipStream_t stream) {
  const float* x    = (const float*)d_in[0];
  const int*   ei   = (const int*)d_in[1];
  const float* W1   = (const float*)d_in[2];
  const float* as1w = (const float*)d_in[3];
  const float* ad1w = (const float*)d_in[4];
  const float* b1   = (const float*)d_in[5];
  const float* W2   = (const float*)d_in[6];
  const float* as2w = (const float*)d_in[7];
  const float* ad2w = (const float*)d_in[8];
  const float* b2   = (const float*)d_in[9];
  float* out = (float*)d_out;

  char* p = (char*)d_ws;
  __half* h1h = (__half*)p; p += (size_t)N_NODES * HID * 2;
  float* o1   = (float*)p; p += (size_t)N_NODES * HID * 4;
  float* a_s1 = (float*)p; p += (size_t)N_NODES * NHEAD * 4;
  float* a_d1 = (float*)p; p += (size_t)N_NODES * NHEAD * 4;
  float* h2   = (float*)p; p += (size_t)N_NODES * 10 * 4;
  float* a_s2 = (float*)p; p += (size_t)N_NODES * 4;
  float* a_d2 = (float*)p; p += (size_t)N_NODES * 4;
  short* Wh   = (short*)p; p += (size_t)KSTEPS * 16 * 64 * 8 * 2;
  short* Wl   = (short*)p; p += (size_t)KSTEPS * 16 * 64 * 8 * 2;
  int* deg    = (int*)p;   p += (size_t)N_NODES * 4;
  int* cur    = (int*)p;   p += (size_t)N_NODES * 4;
  int* off    = (int*)p;   p += (size_t)(N_NODES + 1) * 4;
  int* csr    = (int*)p;   p += (size_t)EL * 4;
  float* p1   = (float*)p; p += (size_t)EL * NHEAD * 4;
  int* btot   = (int*)p;   p += 64 * 4;
  int* bo     = (int*)p;   p += 64 * 4;

  prep_kernel<<<768, 256, 0, stream>>>(W1, Wh, Wl);
  gemm1_mfma_kernel<<<(N_NODES + 63) / 64, 256, 0, stream>>>(
      x, Wh, Wl, h1h, as1w, ad1w, a_s1, a_d1);
  hipMemsetAsync(deg, 0, (size_t)N_NODES * 2 * 4, stream);  // deg + cur (adjacent)
  count_kernel<<<(EL + 255) / 256, 256, 0, stream>>>(ei, deg);
  scan_part_kernel<<<NB_SCAN, 1024, 0, stream>>>(deg, off, btot);
  scan_tops_kernel<<<1, 64, 0, stream>>>(btot, bo);
  scan_add_kernel<<<(N_NODES + 256) / 256, 256, 0, stream>>>(off, bo);
  fill_p1_kernel<<<(EL + 255) / 256, 256, 0, stream>>>(ei, off, cur, a_s1, a_d1, csr, p1);
  agg1_kernel<<<(N_NODES + 1) / 2, 256, 0, stream>>>(h1h, p1, off, csr, b1, o1);
  lin2_kernel<<<(N_NODES + 3) / 4, 256, 0, stream>>>(o1, W2, as2w, ad2w, h2, a_s2, a_d2);
  agg2_kernel<<<(N_NODES + 3) / 4, 256, 0, stream>>>(h2, a_s2, a_d2, off, csr, b2, out);
}

// Round 8
// 374.162 us; speedup vs baseline: 1.8212x; 1.4295x over previous
//
#include <hip/hip_runtime.h>
#include <hip/hip_fp16.h>

#define N_NODES 50000
#define N_EDGES 800000
#define EL (N_EDGES + N_NODES) /* 850000 */
#define F_IN 767
#define HID 256
#define NHEAD 8
#define KSTEPS 24 /* ceil(767/32) */
#define NB_SCAN 49 /* ceil(50000/1024) */

typedef __attribute__((ext_vector_type(8))) short short8;
typedef __attribute__((ext_vector_type(4))) float f32x4;

static __device__ __forceinline__ unsigned short f2bf(float f) {
  unsigned int u = __float_as_uint(f);
  unsigned int r = (u + 0x7fffu + ((u >> 16) & 1u)) >> 16;
  return (unsigned short)r;
}
static __device__ __forceinline__ float bf2f(unsigned short h) {
  return __uint_as_float(((unsigned int)h) << 16);
}

// ---- prep: split W into bf16 hi/lo and repack into MFMA fragment order ----
__global__ __launch_bounds__(256) void prep_kernel(
    const float* __restrict__ W, short* __restrict__ Wh, short* __restrict__ Wl) {
  int idx = blockIdx.x * 256 + threadIdx.x;  // 768*256 threads
  int k = idx >> 8, n = idx & 255;
  float v = (k < F_IN) ? W[k * HID + n] : 0.f;
  unsigned short h = f2bf(v);
  float lf = v - bf2f(h);
  unsigned short lo = f2bf(lf);
  int ks = k >> 5, oct = (k >> 3) & 3, j = k & 7;
  int nf = n >> 4;
  int l = (n & 15) | (oct << 4);
  int addr = ((ks * 16 + nf) * 64 + l) * 8 + j;
  Wh[addr] = (short)h;
  Wl[addr] = (short)lo;
}

// ---- GEMM1: champion structure (R5-bench, 148us) + 3-pass MFMA ordering
//      + branch-hoisted x loads. 1 barrier/ks, dbuf LDS, depth-2 x prefetch,
//      B prefetch 1 ks ahead, fused as1/ad1 epilogue.
__global__ __launch_bounds__(256, 2) void gemm1_mfma_kernel(
    const float* __restrict__ x, const short* __restrict__ Wh,
    const short* __restrict__ Wl, __half* __restrict__ h1h,
    const float* __restrict__ att_s, const float* __restrict__ att_d,
    float* __restrict__ as1, float* __restrict__ ad1) {
  // double-buffered A LDS, XOR-swizzled 16B units: us = u ^ (((u>>4)&3)<<1)
  __shared__ __align__(16) short Ah[2][2048];
  __shared__ __align__(16) short Al[2][2048];
  const int tid = threadIdx.x;
  const int lane = tid & 63, wav = tid >> 6;
  const int m0 = blockIdx.x * 64;
  const int m_local = tid >> 2, oct = tid & 3;
  const int gm = m0 + m_local;
  const bool vrow = (gm < N_NODES);
  const long xbase = (long)gm * F_IN;
  const int wu0 = ((m_local >> 4) * 64) + ((m_local & 15) | (oct << 4));
  const int wu = wu0 ^ ((((unsigned)wu0 >> 4) & 3) << 1);

  float atts[4], attd[4];
#pragma unroll
  for (int nf = 0; nf < 4; ++nf) {
    int c = wav * 64 + nf * 16 + (lane & 15);
    atts[nf] = att_s[c];
    attd[nf] = att_d[c];
  }

  f32x4 acc[4][4];
#pragma unroll
  for (int i = 0; i < 4; ++i)
#pragma unroll
    for (int j = 0; j < 4; ++j) acc[i][j] = (f32x4){0.f, 0.f, 0.f, 0.f};

  // depth-2 x prefetch (branch-hoisted loads so LLVM can widen)
  float xr0[8], xr1[8];
  {
    int kb = oct * 8;
    if (vrow) {
#pragma unroll
      for (int j = 0; j < 8; ++j) xr0[j] = x[xbase + kb + j];
#pragma unroll
      for (int j = 0; j < 8; ++j) xr1[j] = x[xbase + 32 + kb + j];
    } else {
#pragma unroll
      for (int j = 0; j < 8; ++j) { xr0[j] = 0.f; xr1[j] = 0.f; }
    }
  }
  // B prefetch for ks=0
  short8 bhc[4], blc[4];
  {
    const short* wb = Wh + ((wav * 4) * 64 + lane) * 8;
    const short* wbl = Wl + ((wav * 4) * 64 + lane) * 8;
#pragma unroll
    for (int nf = 0; nf < 4; ++nf) {
      bhc[nf] = *(const short8*)(wb + nf * 512);
      blc[nf] = *(const short8*)(wbl + nf * 512);
    }
  }

#pragma unroll 2
  for (int ks = 0; ks < KSTEPS; ++ks) {
    // convert current x regs -> bf16 hi/lo, write to LDS buf[ks&1]
    short8 hi8, lo8;
#pragma unroll
    for (int j = 0; j < 8; ++j) {
      unsigned short h = f2bf(xr0[j]);
      float lf = xr0[j] - bf2f(h);
      hi8[j] = (short)h;
      lo8[j] = (short)f2bf(lf);
    }
    *(short8*)&Ah[ks & 1][wu * 8] = hi8;
    *(short8*)&Al[ks & 1][wu * 8] = lo8;
    // rotate prefetch regs; issue x load for ks+2
    {
      int s = ks + 2;
#pragma unroll
      for (int j = 0; j < 8; ++j) xr0[j] = xr1[j];
      if (s < KSTEPS - 1) {
        int kb = s * 32 + oct * 8;
        if (vrow) {
#pragma unroll
          for (int j = 0; j < 8; ++j) xr1[j] = x[xbase + kb + j];
        } else {
#pragma unroll
          for (int j = 0; j < 8; ++j) xr1[j] = 0.f;
        }
      } else if (s == KSTEPS - 1) {
        int kb = s * 32 + oct * 8;
#pragma unroll
        for (int j = 0; j < 8; ++j) {
          int k = kb + j;
          xr1[j] = (vrow && k < F_IN) ? x[xbase + k] : 0.f;
        }
      }
    }
    __syncthreads();
    // A fragments from LDS (swizzled units; conflict-free)
    short8 ah[4], al[4];
#pragma unroll
    for (int mf = 0; mf < 4; ++mf) {
      int u = mf * 64 + lane;
      int us = u ^ ((((unsigned)u >> 4) & 3) << 1);
      ah[mf] = *(short8*)&Ah[ks & 1][us * 8];
      al[mf] = *(short8*)&Al[ks & 1][us * 8];
    }
    // B prefetch for ks+1 (in flight across the MFMA block)
    short8 bhn[4], bln[4];
    if (ks + 1 < KSTEPS) {
      const short* wb = Wh + (((ks + 1) * 16 + wav * 4) * 64 + lane) * 8;
      const short* wbl = Wl + (((ks + 1) * 16 + wav * 4) * 64 + lane) * 8;
#pragma unroll
      for (int nf = 0; nf < 4; ++nf) {
        bhn[nf] = *(const short8*)(wb + nf * 512);
        bln[nf] = *(const short8*)(wbl + nf * 512);
      }
    }
    // 3 passes of 16 independent MFMAs (dep distance 16 >> MFMA latency)
#pragma unroll
    for (int mf = 0; mf < 4; ++mf)
#pragma unroll
      for (int nf = 0; nf < 4; ++nf)
        acc[mf][nf] = __builtin_amdgcn_mfma_f32_16x16x32_bf16(ah[mf], bhc[nf], acc[mf][nf], 0, 0, 0);
#pragma unroll
    for (int mf = 0; mf < 4; ++mf)
#pragma unroll
      for (int nf = 0; nf < 4; ++nf)
        acc[mf][nf] = __builtin_amdgcn_mfma_f32_16x16x32_bf16(ah[mf], blc[nf], acc[mf][nf], 0, 0, 0);
#pragma unroll
    for (int mf = 0; mf < 4; ++mf)
#pragma unroll
      for (int nf = 0; nf < 4; ++nf)
        acc[mf][nf] = __builtin_amdgcn_mfma_f32_16x16x32_bf16(al[mf], bhc[nf], acc[mf][nf], 0, 0, 0);
#pragma unroll
    for (int nf = 0; nf < 4; ++nf) {
      bhc[nf] = bhn[nf];
      blc[nf] = bln[nf];
    }
  }

  // epilogue: h1 (fp16) store + fused as1/ad1 reduction
  const int r0 = (lane >> 4) * 4, cn = lane & 15;
#pragma unroll
  for (int mf = 0; mf < 4; ++mf) {
    int rowb = m0 + mf * 16 + r0;
#pragma unroll
    for (int rr = 0; rr < 4; ++rr) {
      int row = rowb + rr;
      bool ok = (row < N_NODES);
      if (ok) {
#pragma unroll
        for (int nf = 0; nf < 4; ++nf)
          h1h[(long)row * HID + wav * 64 + nf * 16 + cn] =
              __float2half_rn(acc[mf][nf][rr]);
      }
      float s0 = acc[mf][0][rr] * atts[0] + acc[mf][1][rr] * atts[1];
      float s1 = acc[mf][2][rr] * atts[2] + acc[mf][3][rr] * atts[3];
      float d0 = acc[mf][0][rr] * attd[0] + acc[mf][1][rr] * attd[1];
      float d1 = acc[mf][2][rr] * attd[2] + acc[mf][3][rr] * attd[3];
#pragma unroll
      for (int o = 1; o < 16; o <<= 1) {
        s0 += __shfl_xor(s0, o, 64);
        s1 += __shfl_xor(s1, o, 64);
        d0 += __shfl_xor(d0, o, 64);
        d1 += __shfl_xor(d1, o, 64);
      }
      if (ok && cn == 0) {
        as1[row * NHEAD + wav * 2]     = s0;
        as1[row * NHEAD + wav * 2 + 1] = s1;
        ad1[row * NHEAD + wav * 2]     = d0;
        ad1[row * NHEAD + wav * 2 + 1] = d1;
      }
    }
  }
}

// ---------------- CSR build ----------------
__global__ void count_kernel(const int* __restrict__ ei, int* __restrict__ deg) {
  int e = blockIdx.x * blockDim.x + threadIdx.x;
  if (e >= EL) return;
  int dst = (e < N_EDGES) ? ei[N_EDGES + e] : (e - N_EDGES);
  atomicAdd(&deg[dst], 1);
}

__global__ __launch_bounds__(1024) void scan_part_kernel(
    const int* __restrict__ deg, int* __restrict__ off, int* __restrict__ btot) {
  __shared__ int warp_sums[16];
  const int tid = threadIdx.x;
  const int lane = tid & 63, wid = tid >> 6;
  int i = blockIdx.x * 1024 + tid;
  int v = (i < N_NODES) ? deg[i] : 0;
  int x = v;
#pragma unroll
  for (int o = 1; o < 64; o <<= 1) {
    int y = __shfl_up(x, o, 64);
    if (lane >= o) x += y;
  }
  if (lane == 63) warp_sums[wid] = x;
  __syncthreads();
  if (wid == 0) {
    int ws = (lane < 16) ? warp_sums[lane] : 0;
#pragma unroll
    for (int o = 1; o < 16; o <<= 1) {
      int y = __shfl_up(ws, o, 64);
      if (lane >= o) ws += y;
    }
    if (lane < 16) warp_sums[lane] = ws;
  }
  __syncthreads();
  int wprefix = (wid > 0) ? warp_sums[wid - 1] : 0;
  if (i < N_NODES) off[i] = wprefix + x - v;
  if (tid == 1023) btot[blockIdx.x] = warp_sums[15];
}

__global__ __launch_bounds__(64) void scan_tops_kernel(
    const int* __restrict__ btot, int* __restrict__ bo) {
  int lane = threadIdx.x;
  int v = (lane < NB_SCAN) ? btot[lane] : 0;
  int x = v;
#pragma unroll
  for (int o = 1; o < 64; o <<= 1) {
    int y = __shfl_up(x, o, 64);
    if (lane >= o) x += y;
  }
  if (lane < NB_SCAN) bo[lane] = x - v;  // exclusive
}

__global__ void scan_add_kernel(int* __restrict__ off, const int* __restrict__ bo) {
  int i = blockIdx.x * blockDim.x + threadIdx.x;
  if (i > N_NODES) return;
  if (i == N_NODES) off[i] = EL;
  else off[i] += bo[i >> 10];
}

// ---- fill CSR + per-edge layer-1 softmax numerators (no-max exp) ----
// Logits e = as+ad ~ N(0,~1.1): |e| < ~7 over 6.8M samples -> exp safe in fp32.
__global__ void fill_p1_kernel(const int* __restrict__ ei, const int* __restrict__ off,
                               int* __restrict__ cur, const float* __restrict__ as1,
                               const float* __restrict__ ad1, int* __restrict__ csr,
                               float* __restrict__ p1) {
  int e = blockIdx.x * blockDim.x + threadIdx.x;
  if (e >= EL) return;
  int src, dst;
  if (e < N_EDGES) { src = ei[e]; dst = ei[N_EDGES + e]; }
  else { src = e - N_EDGES; dst = src; }
  int slot = off[dst] + atomicAdd(&cur[dst], 1);
  csr[slot] = src;
  float4 s0 = *(const float4*)&as1[src * NHEAD];
  float4 s1 = *(const float4*)&as1[src * NHEAD + 4];
  float4 d0 = *(const float4*)&ad1[dst * NHEAD];
  float4 d1 = *(const float4*)&ad1[dst * NHEAD + 4];
  float ev[8] = {s0.x + d0.x, s0.y + d0.y, s0.z + d0.z, s0.w + d0.w,
                 s1.x + d1.x, s1.y + d1.y, s1.z + d1.z, s1.w + d1.w};
  float pv[8];
#pragma unroll
  for (int h = 0; h < 8; ++h) {
    float t = ev[h];
    t = (t >= 0.f) ? t : 0.2f * t;
    pv[h] = __expf(t);
  }
  *(float4*)&p1[slot * 8]     = make_float4(pv[0], pv[1], pv[2], pv[3]);
  *(float4*)&p1[slot * 8 + 4] = make_float4(pv[4], pv[5], pv[6], pv[7]);
}

// ---- layer-1 aggregation: single pass, precomputed p, half2 gather, 8-unroll ----
__global__ __launch_bounds__(256) void agg1_kernel(
    const __half* __restrict__ h1h, const float* __restrict__ p1,
    const int* __restrict__ off, const int* __restrict__ csr,
    const float* __restrict__ b1, float* __restrict__ out1) {
  const int t = threadIdx.x & 127;
  const int n = blockIdx.x * 2 + (threadIdx.x >> 7);
  if (n >= N_NODES) return;
  const int head = t >> 4;
  const int j0 = off[n], j1 = off[n + 1];
  float acc0 = 0.f, acc1 = 0.f, den = 0.f;
  int j = j0;
  for (; j + 7 < j1; j += 8) {
    int s[8];
    float pw[8];
    __half2 v[8];
#pragma unroll
    for (int q = 0; q < 8; ++q) s[q] = csr[j + q];
#pragma unroll
    for (int q = 0; q < 8; ++q) {
      pw[q] = p1[(j + q) * 8 + head];
      v[q] = *(const __half2*)&h1h[s[q] * HID + t * 2];
    }
#pragma unroll
    for (int q = 0; q < 8; ++q) {
      float2 f = __half22float2(v[q]);
      den += pw[q];
      acc0 += pw[q] * f.x;
      acc1 += pw[q] * f.y;
    }
  }
  for (; j < j1; ++j) {
    int s0 = csr[j];
    float p0 = p1[j * 8 + head];
    __half2 v0 = *(const __half2*)&h1h[s0 * HID + t * 2];
    float2 f0 = __half22float2(v0);
    den += p0;
    acc0 += p0 * f0.x;
    acc1 += p0 * f0.y;
  }
  float rden = 1.f / (den + 1e-16f);
  float v0 = acc0 * rden + b1[t * 2];
  float v1 = acc1 * rden + b1[t * 2 + 1];
  out1[n * HID + t * 2]     = (v0 > 0.f) ? v0 : (__expf(v0) - 1.f);
  out1[n * HID + t * 2 + 1] = (v1 > 0.f) ? v1 : (__expf(v1) - 1.f);
}

// ---------------- layer 2 linear + attention coefficients ----------------
__global__ __launch_bounds__(256) void lin2_kernel(
    const float* __restrict__ o1, const float* __restrict__ W2,
    const float* __restrict__ att_s2, const float* __restrict__ att_d2,
    float* __restrict__ h2, float* __restrict__ as2, float* __restrict__ ad2) {
  __shared__ float W2s[HID * 10];
  int tid = threadIdx.x;
  for (int i = tid; i < HID * 10; i += 256) W2s[i] = W2[i];
  __syncthreads();
  int wave = tid >> 6, lane = tid & 63;
  int n = blockIdx.x * 4 + wave;
  if (n >= N_NODES) return;
  float4 xv = *(const float4*)&o1[n * HID + lane * 4];
  float hk[10];
#pragma unroll
  for (int k = 0; k < 10; ++k) {
    float p = xv.x * W2s[(lane * 4 + 0) * 10 + k] +
              xv.y * W2s[(lane * 4 + 1) * 10 + k] +
              xv.z * W2s[(lane * 4 + 2) * 10 + k] +
              xv.w * W2s[(lane * 4 + 3) * 10 + k];
#pragma unroll
    for (int o = 32; o >= 1; o >>= 1) p += __shfl_down(p, o, 64);
    hk[k] = p;
  }
  if (lane == 0) {
    float s = 0.f, d = 0.f;
#pragma unroll
    for (int k = 0; k < 10; ++k) {
      h2[n * 10 + k] = hk[k];
      s += hk[k] * att_s2[k];
      d += hk[k] * att_d2[k];
    }
    as2[n] = s;
    ad2[n] = d;
  }
}

// ---------------- layer-2 aggregation (exp fused, single pass) ----------------
__global__ __launch_bounds__(256) void agg2_kernel(
    const float* __restrict__ h2, const float* __restrict__ as2,
    const float* __restrict__ ad2, const int* __restrict__ off,
    const int* __restrict__ csr, const float* __restrict__ b2,
    float* __restrict__ out) {
  int wave = threadIdx.x >> 6, lane = threadIdx.x & 63;
  int n = blockIdx.x * 4 + wave;
  if (n >= N_NODES) return;
  float adn = ad2[n];
  int j0 = off[n], j1 = off[n + 1];
  float acc = 0.f, den = 0.f;
  int j = j0;
  for (; j + 1 < j1; j += 2) {
    int s0 = csr[j], s1 = csr[j + 1];
    float e0 = as2[s0] + adn, e1 = as2[s1] + adn;
    e0 = (e0 >= 0.f) ? e0 : 0.2f * e0;
    e1 = (e1 >= 0.f) ? e1 : 0.2f * e1;
    float p0 = __expf(e0), p1v = __expf(e1);
    den += p0 + p1v;
    if (lane < 10) acc += p0 * h2[s0 * 10 + lane] + p1v * h2[s1 * 10 + lane];
  }
  if (j < j1) {
    int s0 = csr[j];
    float e0 = as2[s0] + adn;
    e0 = (e0 >= 0.f) ? e0 : 0.2f * e0;
    float p0 = __expf(e0);
    den += p0;
    if (lane < 10) acc += p0 * h2[s0 * 10 + lane];
  }
  if (lane < 10) out[n * 10 + lane] = acc / (den + 1e-16f) + b2[lane];
}

extern "C" void kernel_launch(void* const* d_in, const int* in_sizes, int n_in,
                              void* d_out, int out_size, void* d_ws, size_t ws_size,
                              hipStream_t stream) {
  const float* x    = (const float*)d_in[0];
  const int*   ei   = (const int*)d_in[1];
  const float* W1   = (const float*)d_in[2];
  const float* as1w = (const float*)d_in[3];
  const float* ad1w = (const float*)d_in[4];
  const float* b1   = (const float*)d_in[5];
  const float* W2   = (const float*)d_in[6];
  const float* as2w = (const float*)d_in[7];
  const float* ad2w = (const float*)d_in[8];
  const float* b2   = (const float*)d_in[9];
  float* out = (float*)d_out;

  char* p = (char*)d_ws;
  __half* h1h = (__half*)p; p += (size_t)N_NODES * HID * 2;
  float* o1   = (float*)p; p += (size_t)N_NODES * HID * 4;
  float* a_s1 = (float*)p; p += (size_t)N_NODES * NHEAD * 4;
  float* a_d1 = (float*)p; p += (size_t)N_NODES * NHEAD * 4;
  float* h2   = (float*)p; p += (size_t)N_NODES * 10 * 4;
  float* a_s2 = (float*)p; p += (size_t)N_NODES * 4;
  float* a_d2 = (float*)p; p += (size_t)N_NODES * 4;
  short* Wh   = (short*)p; p += (size_t)KSTEPS * 16 * 64 * 8 * 2;
  short* Wl   = (short*)p; p += (size_t)KSTEPS * 16 * 64 * 8 * 2;
  int* deg    = (int*)p;   p += (size_t)N_NODES * 4;
  int* cur    = (int*)p;   p += (size_t)N_NODES * 4;
  int* off    = (int*)p;   p += (size_t)(N_NODES + 1) * 4;
  int* csr    = (int*)p;   p += (size_t)EL * 4;
  float* p1   = (float*)p; p += (size_t)EL * NHEAD * 4;
  int* btot   = (int*)p;   p += 64 * 4;
  int* bo     = (int*)p;   p += 64 * 4;

  prep_kernel<<<768, 256, 0, stream>>>(W1, Wh, Wl);
  gemm1_mfma_kernel<<<(N_NODES + 63) / 64, 256, 0, stream>>>(
      x, Wh, Wl, h1h, as1w, ad1w, a_s1, a_d1);
  hipMemsetAsync(deg, 0, (size_t)N_NODES * 2 * 4, stream);  // deg + cur (adjacent)
  count_kernel<<<(EL + 255) / 256, 256, 0, stream>>>(ei, deg);
  scan_part_kernel<<<NB_SCAN, 1024, 0, stream>>>(deg, off, btot);
  scan_tops_kernel<<<1, 64, 0, stream>>>(btot, bo);
  scan_add_kernel<<<(N_NODES + 256) / 256, 256, 0, stream>>>(off, bo);
  fill_p1_kernel<<<(EL + 255) / 256, 256, 0, stream>>>(ei, off, cur, a_s1, a_d1, csr, p1);
  agg1_kernel<<<(N_NODES + 1) / 2, 256, 0, stream>>>(h1h, p1, off, csr, b1, o1);
  lin2_kernel<<<(N_NODES + 3) / 4, 256, 0, stream>>>(o1, W2, as2w, ad2w, h2, a_s2, a_d2);
  agg2_kernel<<<(N_NODES + 3) / 4, 256, 0, stream>>>(h2, a_s2, a_d2, off, csr, b2, out);
}